// Round 1
// baseline (342.113 us; speedup 1.0000x reference)
//
#include <hip/hip_runtime.h>
#include <math.h>

#define N_NODES 50000
#define N_EDGES 800000
#define F_IN    128
#define D_HID   96
#define NHEAD   8
#define DH      12
#define N_CLS   40
#define NEG_SLOPE 0.2f

// ---------------- CSR build ----------------
__global__ void hist_kernel(const int* __restrict__ dst, int* __restrict__ cnt, int E) {
    int e = blockIdx.x * blockDim.x + threadIdx.x;
    if (e < E) atomicAdd(&cnt[dst[e]], 1);
}

// per-block chunk of 1024 (256 threads x 4 elements): writes within-block inclusive scan
__global__ void scan1_kernel(const int* __restrict__ cnt, int* __restrict__ incl,
                             int* __restrict__ partials, int n) {
    __shared__ int sdata[256];
    int t = threadIdx.x;
    int base = blockIdx.x * 1024 + t * 4;
    int v[4];
#pragma unroll
    for (int j = 0; j < 4; j++) { int i = base + j; v[j] = (i < n) ? cnt[i] : 0; }
    v[1] += v[0]; v[2] += v[1]; v[3] += v[2];
    sdata[t] = v[3];
    __syncthreads();
    for (int off = 1; off < 256; off <<= 1) {
        int x = (t >= off) ? sdata[t - off] : 0;
        __syncthreads();
        sdata[t] += x;
        __syncthreads();
    }
    int excl = sdata[t] - v[3];
#pragma unroll
    for (int j = 0; j < 4; j++) { int i = base + j; if (i < n) incl[i] = v[j] + excl; }
    if (t == 255) partials[blockIdx.x] = sdata[255];
}

__global__ void scan2_kernel(int* partials, int nb) {
    if (threadIdx.x == 0 && blockIdx.x == 0) {
        int run = 0;
        for (int i = 0; i < nb; i++) { int v = partials[i]; partials[i] = run; run += v; }
    }
}

// incl_cursor holds within-block inclusive sums on entry; on exit: cursor[i] = segment start
__global__ void scan3_kernel(const int* __restrict__ cnt, int* __restrict__ incl_cursor,
                             const int* __restrict__ partials, int* __restrict__ rowptr, int n) {
    int i = blockIdx.x * blockDim.x + threadIdx.x;
    if (i >= n) return;
    int v = incl_cursor[i] + partials[i >> 10];
    rowptr[i + 1] = v;
    incl_cursor[i] = v - cnt[i];
    if (i == 0) rowptr[0] = 0;
}

__global__ void fill_kernel(const int* __restrict__ src, const int* __restrict__ dst,
                            int* __restrict__ cursor, int* __restrict__ srclist, int E) {
    int e = blockIdx.x * blockDim.x + threadIdx.x;
    if (e < E) {
        int p = atomicAdd(&cursor[dst[e]], 1);
        srclist[p] = src[e];
    }
}

// ---------------- GEMM (A[M,K] @ W[K,96]) + per-head alpha epilogue ----------------
// BM=128 rows/block, 256 threads: thread (r=tid&31, cg=tid>>5) computes rows {r,r+32,r+64,r+96},
// cols cg*12..cg*12+11 (i.e. head cg's slice).
#define BM 128
#define BK 32
__global__ __launch_bounds__(256) void gemm_alpha_kernel(
    const float* __restrict__ A, const float* __restrict__ W,
    const float* __restrict__ asrc, const float* __restrict__ adst,
    float* __restrict__ Hout, float* __restrict__ aS, float* __restrict__ aD,
    int M, int K)
{
    __shared__ float As[BM][BK + 1];
    __shared__ float Ws[BK][D_HID];
    int tid = threadIdx.x;
    int r   = tid & 31;
    int cg  = tid >> 5;           // head index 0..7
    int n0  = blockIdx.x * BM;

    float acc[4][12];
#pragma unroll
    for (int i = 0; i < 4; i++)
#pragma unroll
        for (int j = 0; j < 12; j++) acc[i][j] = 0.f;

    for (int k0 = 0; k0 < K; k0 += BK) {
        for (int idx = tid; idx < BM * BK; idx += 256) {
            int row = idx >> 5, col = idx & 31;
            int gr = n0 + row;
            As[row][col] = (gr < M) ? A[(size_t)gr * K + k0 + col] : 0.f;
        }
        for (int idx = tid; idx < BK * D_HID; idx += 256) {
            int row = idx / D_HID, col = idx - row * D_HID;
            Ws[row][col] = W[(size_t)(k0 + row) * D_HID + col];
        }
        __syncthreads();
#pragma unroll 4
        for (int kk = 0; kk < BK; kk++) {
            float4 w0 = *(const float4*)&Ws[kk][cg * 12];
            float4 w1 = *(const float4*)&Ws[kk][cg * 12 + 4];
            float4 w2 = *(const float4*)&Ws[kk][cg * 12 + 8];
#pragma unroll
            for (int i = 0; i < 4; i++) {
                float a = As[r + 32 * i][kk];
                acc[i][0] += a * w0.x; acc[i][1] += a * w0.y; acc[i][2]  += a * w0.z; acc[i][3]  += a * w0.w;
                acc[i][4] += a * w1.x; acc[i][5] += a * w1.y; acc[i][6]  += a * w1.z; acc[i][7]  += a * w1.w;
                acc[i][8] += a * w2.x; acc[i][9] += a * w2.y; acc[i][10] += a * w2.z; acc[i][11] += a * w2.w;
            }
        }
        __syncthreads();
    }

    float as_h[12], ad_h[12];
#pragma unroll
    for (int j = 0; j < 12; j++) { as_h[j] = asrc[cg * 12 + j]; ad_h[j] = adst[cg * 12 + j]; }

#pragma unroll
    for (int i = 0; i < 4; i++) {
        int gr = n0 + r + 32 * i;
        if (gr < M) {
            float s_ = 0.f, d_ = 0.f;
            float* op = Hout + (size_t)gr * D_HID + cg * 12;
#pragma unroll
            for (int j = 0; j < 12; j++) {
                op[j] = acc[i][j];
                s_ += acc[i][j] * as_h[j];
                d_ += acc[i][j] * ad_h[j];
            }
            aS[gr * NHEAD + cg] = s_;
            aD[gr * NHEAD + cg] = d_;
        }
    }
}

// ---------------- GAT aggregation: thread per (node, head) ----------------
__global__ __launch_bounds__(256) void gat_aggregate_kernel(
    const float* __restrict__ h, const float* __restrict__ aS, const float* __restrict__ aD,
    const int* __restrict__ rowptr, const int* __restrict__ srclist,
    const float* __restrict__ bias, float* __restrict__ out, int relu)
{
    int gid = blockIdx.x * blockDim.x + threadIdx.x;
    if (gid >= N_NODES * NHEAD) return;
    int n  = gid >> 3;
    int hh = gid & 7;
    int s0 = rowptr[n], s1 = rowptr[n + 1];
    float ad = aD[n * NHEAD + hh];

    float m = -3.402823466e+38f;
    for (int i = s0; i < s1; i++) {
        int s = srclist[i];
        float e = aS[s * NHEAD + hh] + ad;
        e = (e > 0.f) ? e : NEG_SLOPE * e;
        m = fmaxf(m, e);
    }

    float z = 0.f;
    float4 acc0 = {0, 0, 0, 0}, acc1 = {0, 0, 0, 0}, acc2 = {0, 0, 0, 0};
    for (int i = s0; i < s1; i++) {
        int s = srclist[i];
        float e = aS[s * NHEAD + hh] + ad;
        e = (e > 0.f) ? e : NEG_SLOPE * e;
        float p = __expf(e - m);
        z += p;
        const float4* hp = (const float4*)(h + (size_t)s * D_HID + hh * 12);
        float4 h0 = hp[0], h1 = hp[1], h2 = hp[2];
        acc0.x += p * h0.x; acc0.y += p * h0.y; acc0.z += p * h0.z; acc0.w += p * h0.w;
        acc1.x += p * h1.x; acc1.y += p * h1.y; acc1.z += p * h1.z; acc1.w += p * h1.w;
        acc2.x += p * h2.x; acc2.y += p * h2.y; acc2.z += p * h2.z; acc2.w += p * h2.w;
    }

    float inv = 1.f / (z + 1e-16f);
    const float* bp = bias + hh * 12;
    float o[12];
    o[0] = acc0.x * inv + bp[0];  o[1] = acc0.y * inv + bp[1];
    o[2] = acc0.z * inv + bp[2];  o[3] = acc0.w * inv + bp[3];
    o[4] = acc1.x * inv + bp[4];  o[5] = acc1.y * inv + bp[5];
    o[6] = acc1.z * inv + bp[6];  o[7] = acc1.w * inv + bp[7];
    o[8] = acc2.x * inv + bp[8];  o[9] = acc2.y * inv + bp[9];
    o[10] = acc2.z * inv + bp[10]; o[11] = acc2.w * inv + bp[11];
    if (relu) {
#pragma unroll
        for (int j = 0; j < 12; j++) o[j] = fmaxf(o[j], 0.f);
    }
    float4* op = (float4*)(out + (size_t)n * D_HID + hh * 12);
    op[0] = make_float4(o[0], o[1], o[2], o[3]);
    op[1] = make_float4(o[4], o[5], o[6], o[7]);
    op[2] = make_float4(o[8], o[9], o[10], o[11]);
}

// ---------------- final linear (96->40) + bias + log_softmax, thread per node ----------------
__global__ __launch_bounds__(256) void out_lsm_kernel(
    const float* __restrict__ X, const float* __restrict__ Wout,
    const float* __restrict__ bout, float* __restrict__ out)
{
    __shared__ float Ws[D_HID * N_CLS];
    __shared__ float bs[N_CLS];
    for (int i = threadIdx.x; i < D_HID * N_CLS; i += 256) Ws[i] = Wout[i];
    for (int i = threadIdx.x; i < N_CLS; i += 256) bs[i] = bout[i];
    __syncthreads();

    int n = blockIdx.x * blockDim.x + threadIdx.x;
    if (n >= N_NODES) return;

    float acc[N_CLS];
#pragma unroll
    for (int c = 0; c < N_CLS; c++) acc[c] = bs[c];

    const float4* xp = (const float4*)(X + (size_t)n * D_HID);
    for (int k4 = 0; k4 < D_HID / 4; k4++) {
        float4 xv = xp[k4];
        const float* wrow = &Ws[(k4 * 4) * N_CLS];
#pragma unroll
        for (int c4 = 0; c4 < N_CLS / 4; c4++) {
            float4 wa = *(const float4*)(wrow + c4 * 4);
            float4 wb = *(const float4*)(wrow + N_CLS + c4 * 4);
            float4 wc = *(const float4*)(wrow + 2 * N_CLS + c4 * 4);
            float4 wd = *(const float4*)(wrow + 3 * N_CLS + c4 * 4);
            acc[c4 * 4 + 0] += xv.x * wa.x + xv.y * wb.x + xv.z * wc.x + xv.w * wd.x;
            acc[c4 * 4 + 1] += xv.x * wa.y + xv.y * wb.y + xv.z * wc.y + xv.w * wd.y;
            acc[c4 * 4 + 2] += xv.x * wa.z + xv.y * wb.z + xv.z * wc.z + xv.w * wd.z;
            acc[c4 * 4 + 3] += xv.x * wa.w + xv.y * wb.w + xv.z * wc.w + xv.w * wd.w;
        }
    }

    float m = acc[0];
#pragma unroll
    for (int c = 1; c < N_CLS; c++) m = fmaxf(m, acc[c]);
    float s = 0.f;
#pragma unroll
    for (int c = 0; c < N_CLS; c++) s += __expf(acc[c] - m);
    float lg = __logf(s);

    float4* op = (float4*)(out + (size_t)n * N_CLS);
#pragma unroll
    for (int c4 = 0; c4 < N_CLS / 4; c4++) {
        op[c4] = make_float4(acc[c4 * 4 + 0] - m - lg, acc[c4 * 4 + 1] - m - lg,
                             acc[c4 * 4 + 2] - m - lg, acc[c4 * 4 + 3] - m - lg);
    }
}

extern "C" void kernel_launch(void* const* d_in, const int* in_sizes, int n_in,
                              void* d_out, int out_size, void* d_ws, size_t ws_size,
                              hipStream_t stream)
{
    const float* x    = (const float*)d_in[0];
    const int*   esrc = (const int*)d_in[1];
    const int*   edst = (const int*)d_in[2];
    const float* W0   = (const float*)d_in[3];
    const float* as0  = (const float*)d_in[4];
    const float* ad0  = (const float*)d_in[5];
    const float* b0   = (const float*)d_in[6];
    const float* W1   = (const float*)d_in[7];
    const float* as1  = (const float*)d_in[8];
    const float* ad1  = (const float*)d_in[9];
    const float* b1   = (const float*)d_in[10];
    const float* Wout = (const float*)d_in[11];
    const float* bout = (const float*)d_in[12];
    float* out = (float*)d_out;

    char* p = (char*)d_ws;
    float* bufH   = (float*)p; p += (size_t)N_NODES * D_HID * sizeof(float);
    float* bufY   = (float*)p; p += (size_t)N_NODES * D_HID * sizeof(float);
    float* aS     = (float*)p; p += (size_t)N_NODES * NHEAD * sizeof(float);
    float* aD     = (float*)p; p += (size_t)N_NODES * NHEAD * sizeof(float);
    int*   cnt    = (int*)p;   p += ((size_t)N_NODES + 16) * sizeof(int);
    int*   rowptr = (int*)p;   p += ((size_t)N_NODES + 16) * sizeof(int);
    int*   cursor = (int*)p;   p += ((size_t)N_NODES + 16) * sizeof(int);
    int*   srclist= (int*)p;   p += (size_t)N_EDGES * sizeof(int);
    int*   partials=(int*)p;   p += 256;

    // CSR build (by dst)
    hipMemsetAsync(cnt, 0, N_NODES * sizeof(int), stream);
    hist_kernel<<<(N_EDGES + 255) / 256, 256, 0, stream>>>(edst, cnt, N_EDGES);
    int nscan = (N_NODES + 1023) / 1024;
    scan1_kernel<<<nscan, 256, 0, stream>>>(cnt, cursor, partials, N_NODES);
    scan2_kernel<<<1, 64, 0, stream>>>(partials, nscan);
    scan3_kernel<<<(N_NODES + 255) / 256, 256, 0, stream>>>(cnt, cursor, partials, rowptr, N_NODES);
    fill_kernel<<<(N_EDGES + 255) / 256, 256, 0, stream>>>(esrc, edst, cursor, srclist, N_EDGES);

    // layer 0: h0 = x @ W0 (no bias in h), alphas; aggregate + b0 (no relu)
    gemm_alpha_kernel<<<(N_NODES + BM - 1) / BM, 256, 0, stream>>>(
        x, W0, as0, ad0, bufH, aS, aD, N_NODES, F_IN);
    gat_aggregate_kernel<<<(N_NODES * NHEAD + 255) / 256, 256, 0, stream>>>(
        bufH, aS, aD, rowptr, srclist, b0, bufY, 0);

    // layer 1: h1 = y0 @ W1, alphas; aggregate + b1 + relu
    gemm_alpha_kernel<<<(N_NODES + BM - 1) / BM, 256, 0, stream>>>(
        bufY, W1, as1, ad1, bufH, aS, aD, N_NODES, D_HID);
    gat_aggregate_kernel<<<(N_NODES * NHEAD + 255) / 256, 256, 0, stream>>>(
        bufH, aS, aD, rowptr, srclist, b1, bufY, 1);

    // output linear + log_softmax
    out_lsm_kernel<<<(N_NODES + 255) / 256, 256, 0, stream>>>(bufY, Wout, bout, out);
}

// Round 2
// 267.010 us; speedup vs baseline: 1.2813x; 1.2813x over previous
//
#include <hip/hip_runtime.h>
#include <hip/hip_fp16.h>
#include <math.h>

#define N_NODES 50000
#define N_EDGES 800000
#define F_IN    128
#define D_HID   96
#define NHEAD   8
#define DH      12
#define N_CLS   40
#define NEG_SLOPE 0.2f

// ---------------- CSR build ----------------
__global__ void hist_kernel(const int* __restrict__ dst, int* __restrict__ cnt, int E) {
    int e = blockIdx.x * blockDim.x + threadIdx.x;
    if (e < E) atomicAdd(&cnt[dst[e]], 1);
}

__global__ void scan1_kernel(const int* __restrict__ cnt, int* __restrict__ incl,
                             int* __restrict__ partials, int n) {
    __shared__ int sdata[256];
    int t = threadIdx.x;
    int base = blockIdx.x * 1024 + t * 4;
    int v[4];
#pragma unroll
    for (int j = 0; j < 4; j++) { int i = base + j; v[j] = (i < n) ? cnt[i] : 0; }
    v[1] += v[0]; v[2] += v[1]; v[3] += v[2];
    sdata[t] = v[3];
    __syncthreads();
    for (int off = 1; off < 256; off <<= 1) {
        int x = (t >= off) ? sdata[t - off] : 0;
        __syncthreads();
        sdata[t] += x;
        __syncthreads();
    }
    int excl = sdata[t] - v[3];
#pragma unroll
    for (int j = 0; j < 4; j++) { int i = base + j; if (i < n) incl[i] = v[j] + excl; }
    if (t == 255) partials[blockIdx.x] = sdata[255];
}

__global__ void scan2_kernel(int* partials, int nb) {
    if (threadIdx.x == 0 && blockIdx.x == 0) {
        int run = 0;
        for (int i = 0; i < nb; i++) { int v = partials[i]; partials[i] = run; run += v; }
    }
}

__global__ void scan3_kernel(const int* __restrict__ cnt, int* __restrict__ incl_cursor,
                             const int* __restrict__ partials, int* __restrict__ rowptr, int n) {
    int i = blockIdx.x * blockDim.x + threadIdx.x;
    if (i >= n) return;
    int v = incl_cursor[i] + partials[i >> 10];
    rowptr[i + 1] = v;
    incl_cursor[i] = v - cnt[i];
    if (i == 0) rowptr[0] = 0;
}

__global__ void fill_kernel(const int* __restrict__ src, const int* __restrict__ dst,
                            int* __restrict__ cursor, int* __restrict__ srclist, int E) {
    int e = blockIdx.x * blockDim.x + threadIdx.x;
    if (e < E) {
        int p = atomicAdd(&cursor[dst[e]], 1);
        srclist[p] = src[e];
    }
}

// ---------------- GEMM (A[M,K] @ W[K,96]) + per-head alpha epilogue ----------------
// BM=64 rows/block, 256 threads: thread (r=tid&31, cg=tid>>5) computes rows {r, r+32},
// cols cg*12..cg*12+11 (head cg's slice). Writes H as fp16 (gather table) + alpha dots (fp32).
#define BM 64
#define BK 32
__global__ __launch_bounds__(256) void gemm_alpha_kernel(
    const float* __restrict__ A, const float* __restrict__ W,
    const float* __restrict__ asrc, const float* __restrict__ adst,
    __half* __restrict__ Hout, float* __restrict__ aS, float* __restrict__ aD,
    int M, int K)
{
    __shared__ float As[BM][BK + 1];     // 8448 B
    __shared__ float Ws[BK][D_HID];      // 12288 B
    int tid = threadIdx.x;
    int r   = tid & 31;
    int cg  = tid >> 5;           // head index 0..7
    int n0  = blockIdx.x * BM;

    float acc[2][12];
#pragma unroll
    for (int i = 0; i < 2; i++)
#pragma unroll
        for (int j = 0; j < 12; j++) acc[i][j] = 0.f;

    // W loader mapping: thread loads Ws[tid/8][(tid&7)*12 .. +11]
    int wrow = tid >> 3;
    int wcol = (tid & 7) * 12;

    for (int k0 = 0; k0 < K; k0 += BK) {
        for (int idx = tid; idx < BM * BK; idx += 256) {
            int row = idx >> 5, col = idx & 31;
            int gr = n0 + row;
            As[row][col] = (gr < M) ? A[(size_t)gr * K + k0 + col] : 0.f;
        }
        {
            const float* wp = W + (size_t)(k0 + wrow) * D_HID + wcol;
#pragma unroll
            for (int j = 0; j < 12; j++) Ws[wrow][wcol + j] = wp[j];
        }
        __syncthreads();
#pragma unroll 8
        for (int kk = 0; kk < BK; kk++) {
            float4 w0 = *(const float4*)&Ws[kk][cg * 12];
            float4 w1 = *(const float4*)&Ws[kk][cg * 12 + 4];
            float4 w2 = *(const float4*)&Ws[kk][cg * 12 + 8];
            float a0 = As[r][kk];
            float a1 = As[r + 32][kk];
            acc[0][0] += a0 * w0.x; acc[0][1] += a0 * w0.y; acc[0][2]  += a0 * w0.z; acc[0][3]  += a0 * w0.w;
            acc[0][4] += a0 * w1.x; acc[0][5] += a0 * w1.y; acc[0][6]  += a0 * w1.z; acc[0][7]  += a0 * w1.w;
            acc[0][8] += a0 * w2.x; acc[0][9] += a0 * w2.y; acc[0][10] += a0 * w2.z; acc[0][11] += a0 * w2.w;
            acc[1][0] += a1 * w0.x; acc[1][1] += a1 * w0.y; acc[1][2]  += a1 * w0.z; acc[1][3]  += a1 * w0.w;
            acc[1][4] += a1 * w1.x; acc[1][5] += a1 * w1.y; acc[1][6]  += a1 * w1.z; acc[1][7]  += a1 * w1.w;
            acc[1][8] += a1 * w2.x; acc[1][9] += a1 * w2.y; acc[1][10] += a1 * w2.z; acc[1][11] += a1 * w2.w;
        }
        __syncthreads();
    }

    float as_h[12], ad_h[12];
#pragma unroll
    for (int j = 0; j < 12; j++) { as_h[j] = asrc[cg * 12 + j]; ad_h[j] = adst[cg * 12 + j]; }

#pragma unroll
    for (int i = 0; i < 2; i++) {
        int gr = n0 + r + 32 * i;
        if (gr < M) {
            float s_ = 0.f, d_ = 0.f;
#pragma unroll
            for (int j = 0; j < 12; j++) {
                s_ += acc[i][j] * as_h[j];
                d_ += acc[i][j] * ad_h[j];
            }
            __half2* op = (__half2*)(Hout + (size_t)gr * D_HID + cg * 12);
#pragma unroll
            for (int j = 0; j < 6; j++)
                op[j] = __floats2half2_rn(acc[i][2 * j], acc[i][2 * j + 1]);
            aS[gr * NHEAD + cg] = s_;
            aD[gr * NHEAD + cg] = d_;
        }
    }
}

// ---------------- GAT aggregation: thread per (node, head), single pass ----------------
// p = exp(e) without max subtraction: logits bounded (~|e|<5), analytically identical softmax.
__device__ __forceinline__ void agg_edge(const __half* __restrict__ h, int s, int hh,
                                         float p, float* acc) {
    const uint2* hp = (const uint2*)(h + (size_t)s * D_HID + hh * 12);
    uint2 q0 = hp[0], q1 = hp[1], q2 = hp[2];
    float2 f0 = __half22float2(((const __half2*)&q0)[0]);
    float2 f1 = __half22float2(((const __half2*)&q0)[1]);
    float2 f2 = __half22float2(((const __half2*)&q1)[0]);
    float2 f3 = __half22float2(((const __half2*)&q1)[1]);
    float2 f4 = __half22float2(((const __half2*)&q2)[0]);
    float2 f5 = __half22float2(((const __half2*)&q2)[1]);
    acc[0] += p * f0.x; acc[1]  += p * f0.y;
    acc[2] += p * f1.x; acc[3]  += p * f1.y;
    acc[4] += p * f2.x; acc[5]  += p * f2.y;
    acc[6] += p * f3.x; acc[7]  += p * f3.y;
    acc[8] += p * f4.x; acc[9]  += p * f4.y;
    acc[10] += p * f5.x; acc[11] += p * f5.y;
}

__global__ __launch_bounds__(256) void gat_aggregate_kernel(
    const __half* __restrict__ h, const float* __restrict__ aS, const float* __restrict__ aD,
    const int* __restrict__ rowptr, const int* __restrict__ srclist,
    const float* __restrict__ bias, float* __restrict__ out, int relu)
{
    int gid = blockIdx.x * blockDim.x + threadIdx.x;
    if (gid >= N_NODES * NHEAD) return;
    int n  = gid >> 3;
    int hh = gid & 7;
    int s0 = rowptr[n], s1 = rowptr[n + 1];
    float ad = aD[n * NHEAD + hh];

    float z = 0.f;
    float acc[12];
#pragma unroll
    for (int j = 0; j < 12; j++) acc[j] = 0.f;

    int i = s0;
    for (; i + 2 <= s1; i += 2) {
        int sa = srclist[i];
        int sb = srclist[i + 1];
        float ea = aS[sa * NHEAD + hh] + ad;
        float eb = aS[sb * NHEAD + hh] + ad;
        ea = (ea > 0.f) ? ea : NEG_SLOPE * ea;
        eb = (eb > 0.f) ? eb : NEG_SLOPE * eb;
        float pa = __expf(ea);
        float pb = __expf(eb);
        z += pa + pb;
        agg_edge(h, sa, hh, pa, acc);
        agg_edge(h, sb, hh, pb, acc);
    }
    if (i < s1) {
        int sa = srclist[i];
        float ea = aS[sa * NHEAD + hh] + ad;
        ea = (ea > 0.f) ? ea : NEG_SLOPE * ea;
        float pa = __expf(ea);
        z += pa;
        agg_edge(h, sa, hh, pa, acc);
    }

    float inv = 1.f / (z + 1e-16f);
    const float* bp = bias + hh * 12;
    float o[12];
#pragma unroll
    for (int j = 0; j < 12; j++) o[j] = acc[j] * inv + bp[j];
    if (relu) {
#pragma unroll
        for (int j = 0; j < 12; j++) o[j] = fmaxf(o[j], 0.f);
    }
    float4* op = (float4*)(out + (size_t)n * D_HID + hh * 12);
    op[0] = make_float4(o[0], o[1], o[2], o[3]);
    op[1] = make_float4(o[4], o[5], o[6], o[7]);
    op[2] = make_float4(o[8], o[9], o[10], o[11]);
}

// ---------------- final linear (96->40) + bias + log_softmax, thread per node ----------------
__global__ __launch_bounds__(256) void out_lsm_kernel(
    const float* __restrict__ X, const float* __restrict__ Wout,
    const float* __restrict__ bout, float* __restrict__ out)
{
    __shared__ float Ws[D_HID * N_CLS];
    __shared__ float bs[N_CLS];
    for (int i = threadIdx.x; i < D_HID * N_CLS; i += 256) Ws[i] = Wout[i];
    for (int i = threadIdx.x; i < N_CLS; i += 256) bs[i] = bout[i];
    __syncthreads();

    int n = blockIdx.x * blockDim.x + threadIdx.x;
    if (n >= N_NODES) return;

    float acc[N_CLS];
#pragma unroll
    for (int c = 0; c < N_CLS; c++) acc[c] = bs[c];

    const float4* xp = (const float4*)(X + (size_t)n * D_HID);
    for (int k4 = 0; k4 < D_HID / 4; k4++) {
        float4 xv = xp[k4];
        const float* wrow = &Ws[(k4 * 4) * N_CLS];
#pragma unroll
        for (int c4 = 0; c4 < N_CLS / 4; c4++) {
            float4 wa = *(const float4*)(wrow + c4 * 4);
            float4 wb = *(const float4*)(wrow + N_CLS + c4 * 4);
            float4 wc = *(const float4*)(wrow + 2 * N_CLS + c4 * 4);
            float4 wd = *(const float4*)(wrow + 3 * N_CLS + c4 * 4);
            acc[c4 * 4 + 0] += xv.x * wa.x + xv.y * wb.x + xv.z * wc.x + xv.w * wd.x;
            acc[c4 * 4 + 1] += xv.x * wa.y + xv.y * wb.y + xv.z * wc.y + xv.w * wd.y;
            acc[c4 * 4 + 2] += xv.x * wa.z + xv.y * wb.z + xv.z * wc.z + xv.w * wd.z;
            acc[c4 * 4 + 3] += xv.x * wa.w + xv.y * wb.w + xv.z * wc.w + xv.w * wd.w;
        }
    }

    float m = acc[0];
#pragma unroll
    for (int c = 1; c < N_CLS; c++) m = fmaxf(m, acc[c]);
    float s = 0.f;
#pragma unroll
    for (int c = 0; c < N_CLS; c++) s += __expf(acc[c] - m);
    float lg = __logf(s);

    float4* op = (float4*)(out + (size_t)n * N_CLS);
#pragma unroll
    for (int c4 = 0; c4 < N_CLS / 4; c4++) {
        op[c4] = make_float4(acc[c4 * 4 + 0] - m - lg, acc[c4 * 4 + 1] - m - lg,
                             acc[c4 * 4 + 2] - m - lg, acc[c4 * 4 + 3] - m - lg);
    }
}

extern "C" void kernel_launch(void* const* d_in, const int* in_sizes, int n_in,
                              void* d_out, int out_size, void* d_ws, size_t ws_size,
                              hipStream_t stream)
{
    const float* x    = (const float*)d_in[0];
    const int*   esrc = (const int*)d_in[1];
    const int*   edst = (const int*)d_in[2];
    const float* W0   = (const float*)d_in[3];
    const float* as0  = (const float*)d_in[4];
    const float* ad0  = (const float*)d_in[5];
    const float* b0   = (const float*)d_in[6];
    const float* W1   = (const float*)d_in[7];
    const float* as1  = (const float*)d_in[8];
    const float* ad1  = (const float*)d_in[9];
    const float* b1   = (const float*)d_in[10];
    const float* Wout = (const float*)d_in[11];
    const float* bout = (const float*)d_in[12];
    float* out = (float*)d_out;

    char* p = (char*)d_ws;
    float* bufY   = (float*)p; p += (size_t)N_NODES * D_HID * sizeof(float);
    float* aS     = (float*)p; p += (size_t)N_NODES * NHEAD * sizeof(float);
    float* aD     = (float*)p; p += (size_t)N_NODES * NHEAD * sizeof(float);
    __half* bufH  = (__half*)p; p += (size_t)N_NODES * D_HID * sizeof(__half);
    int*   cnt    = (int*)p;   p += ((size_t)N_NODES + 16) * sizeof(int);
    int*   rowptr = (int*)p;   p += ((size_t)N_NODES + 16) * sizeof(int);
    int*   cursor = (int*)p;   p += ((size_t)N_NODES + 16) * sizeof(int);
    int*   srclist= (int*)p;   p += (size_t)N_EDGES * sizeof(int);
    int*   partials=(int*)p;   p += 256;

    // CSR build (by dst)
    hipMemsetAsync(cnt, 0, N_NODES * sizeof(int), stream);
    hist_kernel<<<(N_EDGES + 255) / 256, 256, 0, stream>>>(edst, cnt, N_EDGES);
    int nscan = (N_NODES + 1023) / 1024;
    scan1_kernel<<<nscan, 256, 0, stream>>>(cnt, cursor, partials, N_NODES);
    scan2_kernel<<<1, 64, 0, stream>>>(partials, nscan);
    scan3_kernel<<<(N_NODES + 255) / 256, 256, 0, stream>>>(cnt, cursor, partials, rowptr, N_NODES);
    fill_kernel<<<(N_EDGES + 255) / 256, 256, 0, stream>>>(esrc, edst, cursor, srclist, N_EDGES);

    // layer 0: h0 = x @ W0, alphas; aggregate + b0 (no relu)
    gemm_alpha_kernel<<<(N_NODES + BM - 1) / BM, 256, 0, stream>>>(
        x, W0, as0, ad0, bufH, aS, aD, N_NODES, F_IN);
    gat_aggregate_kernel<<<(N_NODES * NHEAD + 255) / 256, 256, 0, stream>>>(
        bufH, aS, aD, rowptr, srclist, b0, bufY, 0);

    // layer 1: h1 = y0 @ W1, alphas; aggregate + b1 + relu
    gemm_alpha_kernel<<<(N_NODES + BM - 1) / BM, 256, 0, stream>>>(
        bufY, W1, as1, ad1, bufH, aS, aD, N_NODES, D_HID);
    gat_aggregate_kernel<<<(N_NODES * NHEAD + 255) / 256, 256, 0, stream>>>(
        bufH, aS, aD, rowptr, srclist, b1, bufY, 1);

    // output linear + log_softmax
    out_lsm_kernel<<<(N_NODES + 255) / 256, 256, 0, stream>>>(bufY, Wout, bout, out);
}